// Round 1
// baseline (68.277 us; speedup 1.0000x reference)
//
#include <hip/hip_runtime.h>

// EmbeddingShard: out[b,t,:] = kernel_flat[x[b,t],:] + C[s,:] + pos_emb[t,:]
// where s = x / VS and C[s,:] = sum_{s'<s} W[s',VS-1,:] + sum_{s'>s} W[s',0,:] + 8*bias.
// This is exact: clip(x - s'*VS, 0, VS-1) hits row VS-1 for s'<s, row 0 for s'>s,
// and the interior row x - s*VS for s'==s; [SHARDS,VS,D] is contiguous so
// W[s, x mod VS, :] == kernel_flat[x, :].

#define SHARDS 8
#define VS 6300
#define DMODEL 4096
#define SEQ 2048
#define NTOK 8192  // B*SEQ = 4*2048

__global__ __launch_bounds__(256) void precompute_C_kernel(
    const float* __restrict__ kern, const float* __restrict__ bias,
    float* __restrict__ C) {
    int d = blockIdx.x * 256 + threadIdx.x;
    if (d >= DMODEL) return;
    float lo[SHARDS], hi[SHARDS];
#pragma unroll
    for (int s = 0; s < SHARDS; ++s) {
        lo[s] = kern[((size_t)s * VS) * DMODEL + d];               // W[s, 0, d]
        hi[s] = kern[((size_t)s * VS + (VS - 1)) * DMODEL + d];    // W[s, VS-1, d]
    }
    float b8 = 8.0f * bias[d];
    // suffix sums of lo
    float suf = 0.0f;
    float sufs[SHARDS + 1];
    sufs[SHARDS] = 0.0f;
#pragma unroll
    for (int s = SHARDS - 1; s >= 0; --s) { suf += lo[s]; sufs[s] = suf; }
    float pref = 0.0f;
#pragma unroll
    for (int s = 0; s < SHARDS; ++s) {
        C[(size_t)s * DMODEL + d] = pref + sufs[s + 1] + b8;
        pref += hi[s];
    }
}

__global__ __launch_bounds__(256) void embed_kernel(
    const int* __restrict__ x, const float* __restrict__ kern,
    const float* __restrict__ pos_emb, const float* __restrict__ C,
    float* __restrict__ out) {
    int i = blockIdx.x;        // token index 0..NTOK-1
    int t = i & (SEQ - 1);     // sequence position (SEQ is pow2)
    int xv = x[i];             // vocab id, 0..50399
    int s = xv / VS;           // owning shard 0..7

    const float4* __restrict__ wrow = (const float4*)(kern + (size_t)xv * DMODEL);
    const float4* __restrict__ prow = (const float4*)(pos_emb + (size_t)t * DMODEL);
    const float4* __restrict__ crow = (const float4*)(C + (size_t)s * DMODEL);
    float4* __restrict__ orow = (float4*)(out + (size_t)i * DMODEL);

    int tid = threadIdx.x;
#pragma unroll
    for (int j = 0; j < 4; ++j) {
        int d4 = tid + j * 256;      // 1024 float4 per row
        float4 w = wrow[d4];
        float4 p = prow[d4];
        float4 c = crow[d4];
        float4 o;
        o.x = w.x + p.x + c.x;
        o.y = w.y + p.y + c.y;
        o.z = w.z + p.z + c.z;
        o.w = w.w + p.w + c.w;
        orow[d4] = o;
    }
}

extern "C" void kernel_launch(void* const* d_in, const int* in_sizes, int n_in,
                              void* d_out, int out_size, void* d_ws, size_t ws_size,
                              hipStream_t stream) {
    const int*   x       = (const int*)d_in[0];
    const float* kern    = (const float*)d_in[1];
    const float* bias    = (const float*)d_in[2];
    const float* pos_emb = (const float*)d_in[3];
    float*       out     = (float*)d_out;
    float*       C       = (float*)d_ws;   // 8*4096*4 = 128 KiB scratch

    precompute_C_kernel<<<(DMODEL + 255) / 256, 256, 0, stream>>>(kern, bias, C);
    embed_kernel<<<NTOK, 256, 0, stream>>>(x, kern, pos_emb, C, out);
}

// Round 3
// 65.781 us; speedup vs baseline: 1.0379x; 1.0379x over previous
//
#include <hip/hip_runtime.h>

// EmbeddingShard: out[b,t,:] = kernel_flat[x[b,t],:] + C[s,:] + pos_emb[t,:]
// where s = x / VS and C[s,:] = sum_{s'<s} W[s',VS-1,:] + sum_{s'>s} W[s',0,:] + 8*bias.
// Exact: clip(x - s'*VS, 0, VS-1) hits row VS-1 for s'<s, row 0 for s'>s, and the
// interior row x - s*VS for s'==s; [SHARDS,VS,D] contiguous => W[s, x%VS, :] == kernel_flat[x,:].
//
// R1/R2: nontemporal on the 258 MB once-only streams (gather read, out write) so L2
// keeps the reused tables (C: 128 KB, pos_emb: 33.5 MB) resident; batch all loads
// before stores for max memory-level parallelism. R2 fix: use clang ext_vector
// float4 (native vector) — __builtin_nontemporal_* rejects HIP_vector_type structs.

#define SHARDS 8
#define VS 6300
#define DMODEL 4096
#define SEQ 2048
#define NTOK 8192  // B*SEQ = 4*2048

typedef float f4 __attribute__((ext_vector_type(4)));

__global__ __launch_bounds__(256) void precompute_C_kernel(
    const float* __restrict__ kern, const float* __restrict__ bias,
    float* __restrict__ C) {
    int d = blockIdx.x * 256 + threadIdx.x;
    if (d >= DMODEL) return;
    float lo[SHARDS], hi[SHARDS];
#pragma unroll
    for (int s = 0; s < SHARDS; ++s) {
        lo[s] = kern[((size_t)s * VS) * DMODEL + d];               // W[s, 0, d]
        hi[s] = kern[((size_t)s * VS + (VS - 1)) * DMODEL + d];    // W[s, VS-1, d]
    }
    float b8 = 8.0f * bias[d];
    float suf = 0.0f;
    float sufs[SHARDS + 1];
    sufs[SHARDS] = 0.0f;
#pragma unroll
    for (int s = SHARDS - 1; s >= 0; --s) { suf += lo[s]; sufs[s] = suf; }
    float pref = 0.0f;
#pragma unroll
    for (int s = 0; s < SHARDS; ++s) {
        C[(size_t)s * DMODEL + d] = pref + sufs[s + 1] + b8;
        pref += hi[s];
    }
}

__global__ __launch_bounds__(256) void embed_kernel(
    const int* __restrict__ x, const float* __restrict__ kern,
    const float* __restrict__ pos_emb, const float* __restrict__ C,
    float* __restrict__ out) {
    int i = blockIdx.x;        // token index 0..NTOK-1
    int t = i & (SEQ - 1);     // sequence position (SEQ is pow2)
    int xv = x[i];             // vocab id, 0..50399
    int s = xv / VS;           // owning shard 0..7 (const-div -> magic mul)

    const f4* __restrict__ wrow = (const f4*)(kern + (size_t)xv * DMODEL);
    const f4* __restrict__ prow = (const f4*)(pos_emb + (size_t)t * DMODEL);
    const f4* __restrict__ crow = (const f4*)(C + (size_t)s * DMODEL);
    f4* __restrict__ orow = (f4*)(out + (size_t)i * DMODEL);

    int tid = threadIdx.x;
    f4 w[4], p[4], c[4];
    // Issue all 12 loads first (max loads-in-flight per wave).
#pragma unroll
    for (int j = 0; j < 4; ++j)
        w[j] = __builtin_nontemporal_load(&wrow[tid + j * 256]);  // once-only stream
#pragma unroll
    for (int j = 0; j < 4; ++j)
        p[j] = prow[tid + j * 256];                               // reused 4x -> cache
#pragma unroll
    for (int j = 0; j < 4; ++j)
        c[j] = crow[tid + j * 256];                               // tiny table -> cache
#pragma unroll
    for (int j = 0; j < 4; ++j) {
        f4 o = w[j] + p[j] + c[j];
        __builtin_nontemporal_store(o, &orow[tid + j * 256]);     // once-only stream
    }
}

extern "C" void kernel_launch(void* const* d_in, const int* in_sizes, int n_in,
                              void* d_out, int out_size, void* d_ws, size_t ws_size,
                              hipStream_t stream) {
    const int*   x       = (const int*)d_in[0];
    const float* kern    = (const float*)d_in[1];
    const float* bias    = (const float*)d_in[2];
    const float* pos_emb = (const float*)d_in[3];
    float*       out     = (float*)d_out;
    float*       C       = (float*)d_ws;   // 8*4096*4 = 128 KiB scratch

    precompute_C_kernel<<<(DMODEL + 255) / 256, 256, 0, stream>>>(kern, bias, C);
    embed_kernel<<<NTOK, 256, 0, stream>>>(x, kern, pos_emb, C, out);
}

// Round 4
// 61.484 us; speedup vs baseline: 1.1105x; 1.0699x over previous
//
#include <hip/hip_runtime.h>

// EmbeddingShard: out[b,t,:] = kernel_flat[x[b,t],:] + C[s,:] + pos_emb[t,:]
// where s = x / VS and C[s,:] = sum_{s'<s} W[s',VS-1,:] + sum_{s'>s} W[s',0,:] + 8*bias.
// Exact: clip(x - s'*VS, 0, VS-1) hits row VS-1 for s'<s, row 0 for s'>s, and the
// interior row x - s*VS for s'==s; [SHARDS,VS,D] contiguous => W[s, x%VS, :] == kernel_flat[x,:].
//
// R4: 2048 blocks x 4 tokens each. Tokens {t, t+2048, t+4096, t+6144} share one
// pos_emb row (t = i & 2047) -> loaded once to registers, reused 4x. The 4 uniform
// x loads are scalar, issued together (one latency per 4 tokens, not per block).
// 2-deep software pipeline: issue token k+1's NT gather before finishing token k.
// All register arrays statically indexed (hand-unrolled A/B) to avoid scratch.

#define SHARDS 8
#define VS 6300
#define DMODEL 4096
#define SEQ 2048
#define NTOK 8192   // B*SEQ = 4*2048
#define NBLK 2048   // tokens per block = NTOK/NBLK = 4

typedef float f4 __attribute__((ext_vector_type(4)));

__global__ __launch_bounds__(256) void precompute_C_kernel(
    const float* __restrict__ kern, const float* __restrict__ bias,
    float* __restrict__ C) {
    int d = blockIdx.x * 256 + threadIdx.x;
    if (d >= DMODEL) return;
    float lo[SHARDS], hi[SHARDS];
#pragma unroll
    for (int s = 0; s < SHARDS; ++s) {
        lo[s] = kern[((size_t)s * VS) * DMODEL + d];               // W[s, 0, d]
        hi[s] = kern[((size_t)s * VS + (VS - 1)) * DMODEL + d];    // W[s, VS-1, d]
    }
    float b8 = 8.0f * bias[d];
    float suf = 0.0f;
    float sufs[SHARDS + 1];
    sufs[SHARDS] = 0.0f;
#pragma unroll
    for (int s = SHARDS - 1; s >= 0; --s) { suf += lo[s]; sufs[s] = suf; }
    float pref = 0.0f;
#pragma unroll
    for (int s = 0; s < SHARDS; ++s) {
        C[(size_t)s * DMODEL + d] = pref + sufs[s + 1] + b8;
        pref += hi[s];
    }
}

__global__ __launch_bounds__(256) void embed_kernel(
    const int* __restrict__ x, const float* __restrict__ kern,
    const float* __restrict__ pos_emb, const float* __restrict__ C,
    float* __restrict__ out) {
    const int b   = blockIdx.x;    // 0..2047 == sequence position t
    const int tid = threadIdx.x;

    // Uniform token ids for this block's 4 tokens (scalar loads, issued together).
    const int xv0 = x[b];
    const int xv1 = x[b + NBLK];
    const int xv2 = x[b + 2 * NBLK];
    const int xv3 = x[b + 3 * NBLK];
    const int s0 = xv0 / VS, s1 = xv1 / VS, s2 = xv2 / VS, s3 = xv3 / VS;

    const f4* __restrict__ w0 = (const f4*)(kern + (size_t)xv0 * DMODEL);
    const f4* __restrict__ w1 = (const f4*)(kern + (size_t)xv1 * DMODEL);
    const f4* __restrict__ w2 = (const f4*)(kern + (size_t)xv2 * DMODEL);
    const f4* __restrict__ w3 = (const f4*)(kern + (size_t)xv3 * DMODEL);
    const f4* __restrict__ c0 = (const f4*)(C + (size_t)s0 * DMODEL);
    const f4* __restrict__ c1 = (const f4*)(C + (size_t)s1 * DMODEL);
    const f4* __restrict__ c2 = (const f4*)(C + (size_t)s2 * DMODEL);
    const f4* __restrict__ c3 = (const f4*)(C + (size_t)s3 * DMODEL);
    const f4* __restrict__ pr = (const f4*)(pos_emb + (size_t)b * DMODEL);

    f4 p[4];
#pragma unroll
    for (int j = 0; j < 4; ++j) p[j] = pr[tid + j * 256];   // shared by all 4 tokens

    f4 wA[4], cA[4], wB[4], cB[4];

#define ISSUE(WROW, CROW, W, Cc)                                      \
    _Pragma("unroll") for (int j = 0; j < 4; ++j)                     \
        W[j] = __builtin_nontemporal_load(&WROW[tid + j * 256]);      \
    _Pragma("unroll") for (int j = 0; j < 4; ++j)                     \
        Cc[j] = CROW[tid + j * 256];

#define FINISH(K, W, Cc)                                              \
    {                                                                 \
        f4* __restrict__ orow = (f4*)(out + (size_t)(b + (K) * NBLK) * DMODEL); \
        _Pragma("unroll") for (int j = 0; j < 4; ++j) {               \
            f4 o = W[j] + p[j] + Cc[j];                               \
            __builtin_nontemporal_store(o, &orow[tid + j * 256]);     \
        }                                                             \
    }

    ISSUE(w0, c0, wA, cA)
    ISSUE(w1, c1, wB, cB)
    FINISH(0, wA, cA)
    ISSUE(w2, c2, wA, cA)
    FINISH(1, wB, cB)
    ISSUE(w3, c3, wB, cB)
    FINISH(2, wA, cA)
    FINISH(3, wB, cB)

#undef ISSUE
#undef FINISH
}

extern "C" void kernel_launch(void* const* d_in, const int* in_sizes, int n_in,
                              void* d_out, int out_size, void* d_ws, size_t ws_size,
                              hipStream_t stream) {
    const int*   x       = (const int*)d_in[0];
    const float* kern    = (const float*)d_in[1];
    const float* bias    = (const float*)d_in[2];
    const float* pos_emb = (const float*)d_in[3];
    float*       out     = (float*)d_out;
    float*       C       = (float*)d_ws;   // 8*4096*4 = 128 KiB scratch

    precompute_C_kernel<<<(DMODEL + 255) / 256, 256, 0, stream>>>(kern, bias, C);
    embed_kernel<<<NBLK, 256, 0, stream>>>(x, kern, pos_emb, C, out);
}